// Round 3
// baseline (1679.566 us; speedup 1.0000x reference)
//
#include <hip/hip_runtime.h>
#include <math.h>

// ============================================================================
// R3 = R2 + bugfix: phase_gates computed the U-term unconditionally, so the
// layer-1 h-gate (g==2) got a spurious extra Uh1@Q1 (hcap = Wh@zt + Uh@Q +
// Uh@(r*Q) instead of Wh@zt + Uh@(r*Q)) -> absmax 10.9. U-term now g<2 only.
// ============================================================================

typedef unsigned short u16;
typedef __attribute__((ext_vector_type(8))) short bhalf8;   // 8 bf16 = 4 VGPR
typedef __attribute__((ext_vector_type(16))) float f32x16;  // 32x32 mfma acc

__device__ __forceinline__ void split2(float f, unsigned &h, unsigned &l){
  unsigned u = __float_as_uint(f);
  h = u >> 16;                                    // truncated hi bf16
  float r = f - __uint_as_float(u & 0xFFFF0000u); // exact residual
  l = __float_as_uint(r) >> 16;                   // lo bf16
}

// LDS tile: [rows][64 k] bf16, row stride 128 B, XOR swizzle on 16B granules.
__device__ __forceinline__ int swz64(int row, int kb){
  return (row << 7) + (kb ^ ((row & 7) << 4));
}

__device__ __forceinline__ bhalf8 frag(const u16* s, int row, int kb){
  return *(const bhalf8*)((const char*)s + swz64(row, kb));
}

__device__ __forceinline__ f32x16 mm3(bhalf8 ah, bhalf8 al, bhalf8 bh, bhalf8 bl, f32x16 acc){
  acc = __builtin_amdgcn_mfma_f32_32x32x16_bf16(ah, bh, acc, 0, 0, 0);
  acc = __builtin_amdgcn_mfma_f32_32x32x16_bf16(ah, bl, acc, 0, 0, 0);
  acc = __builtin_amdgcn_mfma_f32_32x32x16_bf16(al, bh, acc, 0, 0, 0);
  return acc;
}

// stage rows x 64 tile pair from fp32 source (+optional per-row scale), split.
__device__ __forceinline__ void stage_f32s(const float* src, long ld, int rows, long k0,
                                           const float* scale, u16* sH, u16* sL, int tid){
  int rb = tid >> 2, ke = (tid & 3) << 4;
  for (int r0 = 0; r0 < rows; r0 += 64){
    int r = r0 + rb; if (r >= rows) break;
    const float* p = src + (long)r*ld + k0 + ke;
    float sc = scale ? scale[r] : 1.0f;
    unsigned hh[16], ll[16];
    #pragma unroll
    for (int q = 0; q < 4; q++){
      float4 v = *(const float4*)(p + q*4);
      split2(v.x*sc, hh[q*4+0], ll[q*4+0]); split2(v.y*sc, hh[q*4+1], ll[q*4+1]);
      split2(v.z*sc, hh[q*4+2], ll[q*4+2]); split2(v.w*sc, hh[q*4+3], ll[q*4+3]);
    }
    uint4 p0, p1, q0, q1;
    p0.x = hh[0]|(hh[1]<<16);  p0.y = hh[2]|(hh[3]<<16);  p0.z = hh[4]|(hh[5]<<16);  p0.w = hh[6]|(hh[7]<<16);
    p1.x = hh[8]|(hh[9]<<16);  p1.y = hh[10]|(hh[11]<<16);p1.z = hh[12]|(hh[13]<<16);p1.w = hh[14]|(hh[15]<<16);
    q0.x = ll[0]|(ll[1]<<16);  q0.y = ll[2]|(ll[3]<<16);  q0.z = ll[4]|(ll[5]<<16);  q0.w = ll[6]|(ll[7]<<16);
    q1.x = ll[8]|(ll[9]<<16);  q1.y = ll[10]|(ll[11]<<16);q1.z = ll[12]|(ll[13]<<16);q1.w = ll[14]|(ll[15]<<16);
    int o0 = swz64(r, ke << 1), o1 = swz64(r, (ke << 1) + 16);
    *(uint4*)((char*)sH + o0) = p0; *(uint4*)((char*)sH + o1) = p1;
    *(uint4*)((char*)sL + o0) = q0; *(uint4*)((char*)sL + o1) = q1;
  }
}

// stage rows x 64 tile pair from pre-split bf16 hi/lo sources (copy).
__device__ __forceinline__ void stage_cp(const u16* srcH, const u16* srcL, long ld, int rows,
                                         long k0, u16* sH, u16* sL, int tid){
  int rb = tid >> 2, ke = (tid & 3) << 4;
  for (int r0 = 0; r0 < rows; r0 += 64){
    int r = r0 + rb; if (r >= rows) break;
    long g = (long)r*ld + k0 + ke;
    uint4 a = *(const uint4*)(srcH + g), b = *(const uint4*)(srcH + g + 8);
    uint4 c = *(const uint4*)(srcL + g), d = *(const uint4*)(srcL + g + 8);
    int o0 = swz64(r, ke << 1), o1 = swz64(r, (ke << 1) + 16);
    *(uint4*)((char*)sH + o0) = a; *(uint4*)((char*)sH + o1) = b;
    *(uint4*)((char*)sL + o0) = c; *(uint4*)((char*)sL + o1) = d;
  }
}

// stage rows x 64 tile pair = elementwise product of two fp32 sources, split.
__device__ __forceinline__ void stage_prod(const float* a, const float* b, long ld, int rows,
                                           long k0, u16* sH, u16* sL, int tid){
  int rb = tid >> 2, ke = (tid & 3) << 4;
  for (int r0 = 0; r0 < rows; r0 += 64){
    int r = r0 + rb; if (r >= rows) break;
    const float* pa = a + (long)r*ld + k0 + ke;
    const float* pb = b + (long)r*ld + k0 + ke;
    unsigned hh[16], ll[16];
    #pragma unroll
    for (int q = 0; q < 4; q++){
      float4 va = *(const float4*)(pa + q*4);
      float4 vb = *(const float4*)(pb + q*4);
      split2(va.x*vb.x, hh[q*4+0], ll[q*4+0]); split2(va.y*vb.y, hh[q*4+1], ll[q*4+1]);
      split2(va.z*vb.z, hh[q*4+2], ll[q*4+2]); split2(va.w*vb.w, hh[q*4+3], ll[q*4+3]);
    }
    uint4 p0, p1, q0, q1;
    p0.x = hh[0]|(hh[1]<<16);  p0.y = hh[2]|(hh[3]<<16);  p0.z = hh[4]|(hh[5]<<16);  p0.w = hh[6]|(hh[7]<<16);
    p1.x = hh[8]|(hh[9]<<16);  p1.y = hh[10]|(hh[11]<<16);p1.z = hh[12]|(hh[13]<<16);p1.w = hh[14]|(hh[15]<<16);
    q0.x = ll[0]|(ll[1]<<16);  q0.y = ll[2]|(ll[3]<<16);  q0.z = ll[4]|(ll[5]<<16);  q0.w = ll[6]|(ll[7]<<16);
    q1.x = ll[8]|(ll[9]<<16);  q1.y = ll[10]|(ll[11]<<16);q1.z = ll[12]|(ll[13]<<16);q1.w = ll[14]|(ll[15]<<16);
    int o0 = swz64(r, ke << 1), o1 = swz64(r, (ke << 1) + 16);
    *(uint4*)((char*)sH + o0) = p0; *(uint4*)((char*)sH + o1) = p1;
    *(uint4*)((char*)sL + o0) = q0; *(uint4*)((char*)sL + o1) = q1;
  }
}

// transposed writes from ldsT[64][65] fp32: dst[j0+jc][m0+...] (ld 256)
__device__ __forceinline__ void twrite_f32(const float* ldsT, float* dst, int m0, int j0, int tid){
  int jc = tid >> 2, seg = tid & 3;
  float* p = dst + (long)(j0 + jc)*256 + m0 + (seg << 4);
  #pragma unroll
  for (int q = 0; q < 4; q++){
    float4 o;
    o.x = ldsT[(seg*16 + q*4 + 0)*65 + jc];
    o.y = ldsT[(seg*16 + q*4 + 1)*65 + jc];
    o.z = ldsT[(seg*16 + q*4 + 2)*65 + jc];
    o.w = ldsT[(seg*16 + q*4 + 3)*65 + jc];
    *(float4*)(p + q*4) = o;
  }
}

__device__ __forceinline__ void twrite_bf16(const float* ldsT, u16* dh, u16* dl, int m0, int j0, int tid){
  int jc = tid >> 2, seg = tid & 3;
  unsigned hh[16], ll[16];
  #pragma unroll
  for (int q = 0; q < 16; q++)
    split2(ldsT[(seg*16 + q)*65 + jc], hh[q], ll[q]);
  uint4 p0, p1, q0, q1;
  p0.x = hh[0]|(hh[1]<<16);  p0.y = hh[2]|(hh[3]<<16);  p0.z = hh[4]|(hh[5]<<16);  p0.w = hh[6]|(hh[7]<<16);
  p1.x = hh[8]|(hh[9]<<16);  p1.y = hh[10]|(hh[11]<<16);p1.z = hh[12]|(hh[13]<<16);p1.w = hh[14]|(hh[15]<<16);
  q0.x = ll[0]|(ll[1]<<16);  q0.y = ll[2]|(ll[3]<<16);  q0.z = ll[4]|(ll[5]<<16);  q0.w = ll[6]|(ll[7]<<16);
  q1.x = ll[8]|(ll[9]<<16);  q1.y = ll[10]|(ll[11]<<16);q1.z = ll[12]|(ll[13]<<16);q1.w = ll[14]|(ll[15]<<16);
  u16* ph = dh + (long)(j0 + jc)*256 + m0 + (seg << 4);
  u16* pl = dl + (long)(j0 + jc)*256 + m0 + (seg << 4);
  ((uint4*)ph)[0] = p0; ((uint4*)ph)[1] = p1;
  ((uint4*)pl)[0] = q0; ((uint4*)pl)[1] = q1;
}

// ---------------------------------------------------------------------------
// norms + barrier init. 1 block.
__launch_bounds__(256)
__global__ void norm_kernel(const float* __restrict__ sc0, const float* __restrict__ sc1,
                            float* __restrict__ sn, int* __restrict__ bar){
  int tid = threadIdx.x;
  __shared__ float s0[256], s1[256];
  float a = sc0[tid], c = sc1[tid];
  s0[tid] = a*a; s1[tid] = c*c; __syncthreads();
  for (int off = 128; off > 0; off >>= 1){
    if (tid < off){ s0[tid] += s0[tid+off]; s1[tid] += s1[tid+off]; }
    __syncthreads();
  }
  if (tid == 0){ sn[0] = sqrtf(s0[0]); sn[1] = sqrtf(s1[0]); *bar = 0; }
}

// ---------------------------------------------------------------------------
// ts[t][j] = tanh(dot(emb_t[j,:], scorer)/sn) for j in 0..255
__launch_bounds__(256)
__global__ void scores_kernel(const float* __restrict__ emb, long embStrideT,
                              const float* __restrict__ scorer,
                              const float* __restrict__ sn, int snIdx,
                              float* __restrict__ ts, int tsStrideT){
  int t = blockIdx.y;
  int wave = threadIdx.x >> 6, lane = threadIdx.x & 63;
  int j = blockIdx.x*4 + wave;
  const float* row = emb + (long)t*embStrideT + (long)j*256;
  float s = 0.f;
  for (int c = lane; c < 256; c += 64) s += row[c] * scorer[c];
  for (int off = 32; off > 0; off >>= 1) s += __shfl_down(s, off);
  if (lane == 0) ts[t*tsStrideT + j] = tanhf(s / sn[snIdx]);
}

// ---------------------------------------------------------------------------
// Q0 init: copy fp32 + transposed fp32 + transposed split bf16. grid (64, 2).
__launch_bounds__(256)
__global__ void prepq_kernel(const float* __restrict__ q0, const float* __restrict__ q1,
                             float* __restrict__ Qf, float* __restrict__ QTf,
                             u16* __restrict__ QTh, u16* __restrict__ QTl){
  int l = blockIdx.y, tid = threadIdx.x;
  const float* src = l ? q1 : q0;
  long base = (long)l * 131072;   // pp = 0
  int bx = blockIdx.x, k0 = (bx >> 3) << 5, j0 = (bx & 7) << 5;
  int c = tid & 31, r = tid >> 5;
  __shared__ float s[32][33];
  #pragma unroll
  for (int i = 0; i < 4; i++){
    int rr = r + 8*i;
    float v = src[(k0+rr)*256 + j0+c];
    s[rr][c] = v;
    Qf[base + (long)(k0+rr)*256 + j0+c] = v;
  }
  __syncthreads();
  #pragma unroll
  for (int i = 0; i < 4; i++){
    int rr = r + 8*i;
    float v = s[c][rr];
    long o = base + (long)(j0+rr)*256 + k0 + c;
    QTf[o] = v;
    unsigned h, lo; split2(v, h, lo);
    QTh[o] = (u16)h; QTl[o] = (u16)lo;
  }
}

// ---------------------------------------------------------------------------
// split 9 static 256x256 matrices into SPL[id][hi/lo]. grid (32, 9).
__launch_bounds__(256)
__global__ void split9_kernel(const float* m0,const float* m1,const float* m2,
                              const float* m3,const float* m4,const float* m5,
                              const float* m6,const float* m7,const float* m8,
                              u16* __restrict__ SPL){
  int z = blockIdx.y;
  const float* src = (z==0)?m0:(z==1)?m1:(z==2)?m2:(z==3)?m3:(z==4)?m4:(z==5)?m5:(z==6)?m6:(z==7)?m7:m8;
  u16* H = SPL + (long)z*131072;
  u16* L = H + 65536;
  int i = blockIdx.x*256 + threadIdx.x;
  long o = (long)i * 8;
  float4 v0 = *(const float4*)(src + o);
  float4 v1 = *(const float4*)(src + o + 4);
  unsigned h0,h1,h2,h3,h4,h5,h6,h7, l0,l1,l2,l3,l4,l5,l6,l7;
  split2(v0.x,h0,l0); split2(v0.y,h1,l1); split2(v0.z,h2,l2); split2(v0.w,h3,l3);
  split2(v1.x,h4,l4); split2(v1.y,h5,l5); split2(v1.z,h6,l6); split2(v1.w,h7,l7);
  uint4 ph, pl;
  ph.x = h0|(h1<<16); ph.y = h2|(h3<<16); ph.z = h4|(h5<<16); ph.w = h6|(h7<<16);
  pl.x = l0|(l1<<16); pl.y = l2|(l3<<16); pl.z = l4|(l5<<16); pl.w = l6|(l7<<16);
  *(uint4*)(H + o) = ph;
  *(uint4*)(L + o) = pl;
}

// ---------------------------------------------------------------------------
// split fp32 -> (hi, lo) bf16 (R1, unchanged).
__launch_bounds__(256)
__global__ void split_kernel(const float* __restrict__ src, long sStride,
                             u16* __restrict__ dh, u16* __restrict__ dl,
                             long dStride, int n8){
  int z = blockIdx.y;
  const float* S = src + (long)z * sStride;
  u16* H = dh + (long)z * dStride;
  u16* L = dl + (long)z * dStride;
  int i = blockIdx.x * 256 + threadIdx.x;
  if (i >= n8) return;
  long o = (long)i * 8;
  float4 v0 = *(const float4*)(S + o);
  float4 v1 = *(const float4*)(S + o + 4);
  unsigned h0,h1,h2,h3,h4,h5,h6,h7, l0,l1,l2,l3,l4,l5,l6,l7;
  split2(v0.x,h0,l0); split2(v0.y,h1,l1); split2(v0.z,h2,l2); split2(v0.w,h3,l3);
  split2(v1.x,h4,l4); split2(v1.y,h5,l5); split2(v1.z,h6,l6); split2(v1.w,h7,l7);
  uint4 ph, pl;
  ph.x = h0|(h1<<16); ph.y = h2|(h3<<16); ph.z = h4|(h5<<16); ph.w = h6|(h7<<16);
  pl.x = l0|(l1<<16); pl.y = l2|(l3<<16); pl.z = l4|(l5<<16); pl.w = l6|(l7<<16);
  *(uint4*)(H + o) = ph;
  *(uint4*)(L + o) = pl;
}

// ---------------------------------------------------------------------------
// transpose + split fp32 [4096][256] -> bf16 hi/lo [256][4096] (R1, unchanged).
__launch_bounds__(256)
__global__ void tconv_kernel(const float* __restrict__ src, long sStride,
                             u16* __restrict__ dh, u16* __restrict__ dl, long dStride){
  int z = blockIdx.z;
  const float* S = src + (long)z * sStride;
  u16* H = dh + (long)z * dStride;
  u16* L = dl + (long)z * dStride;
  int k0 = blockIdx.x << 5, n0 = blockIdx.y << 5;
  int c = threadIdx.x & 31, r = threadIdx.x >> 5;
  __shared__ float s[32][33];
  #pragma unroll
  for (int i = 0; i < 4; i++)
    s[r + 8*i][c] = S[(long)(k0 + r + 8*i) * 256 + n0 + c];
  __syncthreads();
  #pragma unroll
  for (int i = 0; i < 4; i++){
    int rr = r + 8*i;
    unsigned h, l;
    split2(s[c][rr], h, l);
    H[(long)(n0 + rr) * 4096 + k0 + c] = (u16)h;
    L[(long)(n0 + rr) * 4096 + k0 + c] = (u16)l;
  }
}

// ---------------------------------------------------------------------------
// split-bf16 MFMA GEMM K=4096, split-K=4 (R1, unchanged).
__device__ __forceinline__ int swzA(int row, int kb){
  return (row << 7) + (kb ^ ((row & 7) << 4));
}

__launch_bounds__(256, 2)
__global__ void gemm_mfma(const u16* __restrict__ Ah, const u16* __restrict__ Al, long aStride,
                          const u16* __restrict__ Bh, const u16* __restrict__ Bl, long bStride,
                          float* __restrict__ P, long pStride){
  int mt = blockIdx.x, nt = blockIdx.y;
  int z = blockIdx.z >> 2, ks = blockIdx.z & 3;
  long M256 = (long)gridDim.x * 32768;
  const u16* ah = Ah + (long)z * aStride;
  const u16* al = Al + (long)z * aStride;
  const u16* bh = Bh + (long)z * bStride;
  const u16* bl = Bl + (long)z * bStride;
  float* pout = P + (long)z * pStride + (long)ks * M256;

  __shared__ u16 lds[32768];
  u16* sAh = lds;
  u16* sAl = lds + 8192;
  u16* sBh = lds + 16384;
  u16* sBl = lds + 24576;

  int tid  = threadIdx.x;
  int lane = tid & 63, wave = tid >> 6;
  int wm = (wave >> 1) << 6, wn = (wave & 1) << 6;
  int ln31 = lane & 31, lhi = lane >> 5;

  int m0 = mt << 7, n0 = nt << 7;
  int srow = tid >> 3;
  int skE  = (tid & 7) << 3;

  f32x16 acc00, acc01, acc10, acc11;
  #pragma unroll
  for (int i = 0; i < 16; i++){ acc00[i]=0.f; acc01[i]=0.f; acc10[i]=0.f; acc11[i]=0.f; }

  long kbase = (long)ks << 10;
  for (int kk = 0; kk < 16; kk++){
    long k0 = kbase + ((long)kk << 6);
    uint4 ra[4], rb[4], rc[4], rd[4];
    #pragma unroll
    for (int p = 0; p < 4; p++){
      int row = (p << 5) + srow;
      long ga = (long)(m0 + row) * 4096 + k0 + skE;
      long gb = (long)(n0 + row) * 4096 + k0 + skE;
      ra[p] = *(const uint4*)(ah + ga);
      rb[p] = *(const uint4*)(al + ga);
      rc[p] = *(const uint4*)(bh + gb);
      rd[p] = *(const uint4*)(bl + gb);
    }
    #pragma unroll
    for (int p = 0; p < 4; p++){
      int row = (p << 5) + srow;
      int lo = swzA(row, skE << 1);
      *(uint4*)((char*)sAh + lo) = ra[p];
      *(uint4*)((char*)sAl + lo) = rb[p];
      *(uint4*)((char*)sBh + lo) = rc[p];
      *(uint4*)((char*)sBl + lo) = rd[p];
    }
    __syncthreads();
    #pragma unroll
    for (int s = 0; s < 4; s++){
      int kb = (s << 5) + (lhi << 4);
      bhalf8 a0h = *(const bhalf8*)((char*)sAh + swzA(wm + ln31,      kb));
      bhalf8 a1h = *(const bhalf8*)((char*)sAh + swzA(wm + 32 + ln31, kb));
      bhalf8 a0l = *(const bhalf8*)((char*)sAl + swzA(wm + ln31,      kb));
      bhalf8 a1l = *(const bhalf8*)((char*)sAl + swzA(wm + 32 + ln31, kb));
      bhalf8 b0h = *(const bhalf8*)((char*)sBh + swzA(wn + ln31,      kb));
      bhalf8 b1h = *(const bhalf8*)((char*)sBh + swzA(wn + 32 + ln31, kb));
      bhalf8 b0l = *(const bhalf8*)((char*)sBl + swzA(wn + ln31,      kb));
      bhalf8 b1l = *(const bhalf8*)((char*)sBl + swzA(wn + 32 + ln31, kb));
      acc00 = __builtin_amdgcn_mfma_f32_32x32x16_bf16(a0h, b0h, acc00, 0, 0, 0);
      acc01 = __builtin_amdgcn_mfma_f32_32x32x16_bf16(a0h, b1h, acc01, 0, 0, 0);
      acc10 = __builtin_amdgcn_mfma_f32_32x32x16_bf16(a1h, b0h, acc10, 0, 0, 0);
      acc11 = __builtin_amdgcn_mfma_f32_32x32x16_bf16(a1h, b1h, acc11, 0, 0, 0);
      acc00 = __builtin_amdgcn_mfma_f32_32x32x16_bf16(a0h, b0l, acc00, 0, 0, 0);
      acc01 = __builtin_amdgcn_mfma_f32_32x32x16_bf16(a0h, b1l, acc01, 0, 0, 0);
      acc10 = __builtin_amdgcn_mfma_f32_32x32x16_bf16(a1h, b0l, acc10, 0, 0, 0);
      acc11 = __builtin_amdgcn_mfma_f32_32x32x16_bf16(a1h, b1l, acc11, 0, 0, 0);
      acc00 = __builtin_amdgcn_mfma_f32_32x32x16_bf16(a0l, b0h, acc00, 0, 0, 0);
      acc01 = __builtin_amdgcn_mfma_f32_32x32x16_bf16(a0l, b1h, acc01, 0, 0, 0);
      acc10 = __builtin_amdgcn_mfma_f32_32x32x16_bf16(a1l, b0h, acc10, 0, 0, 0);
      acc11 = __builtin_amdgcn_mfma_f32_32x32x16_bf16(a1l, b1h, acc11, 0, 0, 0);
    }
    __syncthreads();
  }
  float* po = pout + (long)(m0 + wm) * 256 + (n0 + wn);
  int rb16 = lhi << 2;
  #pragma unroll
  for (int reg = 0; reg < 16; reg++){
    int r = (reg & 3) + ((reg >> 2) << 3) + rb16;
    po[(long)r * 256 + ln31]              = acc00[reg];
    po[(long)r * 256 + 32 + ln31]         = acc01[reg];
    po[(long)(r + 32) * 256 + ln31]       = acc10[reg];
    po[(long)(r + 32) * 256 + 32 + ln31]  = acc11[reg];
  }
}

// ---------------------------------------------------------------------------
// sum 4 split-K partials (+optional relu) (R1, unchanged).
__launch_bounds__(256)
__global__ void reduce4_kernel(const float* __restrict__ P, long zStrideP, long ksStride,
                               float* __restrict__ out, long zStrideO, int count4, int relu){
  int z = blockIdx.y;
  const float* p = P + (long)z * zStrideP;
  float* o = out + (long)z * zStrideO;
  int i = blockIdx.x * 256 + threadIdx.x;
  if (i >= count4) return;
  long b = (long)i * 4;
  float4 v0 = *(const float4*)(p + b);
  float4 v1 = *(const float4*)(p + ksStride + b);
  float4 v2 = *(const float4*)(p + 2*ksStride + b);
  float4 v3 = *(const float4*)(p + 3*ksStride + b);
  float4 r;
  r.x = v0.x+v1.x+v2.x+v3.x; r.y = v0.y+v1.y+v2.y+v3.y;
  r.z = v0.z+v1.z+v2.z+v3.z; r.w = v0.w+v1.w+v2.w+v3.w;
  if (relu){ r.x=fmaxf(r.x,0.f); r.y=fmaxf(r.y,0.f); r.z=fmaxf(r.z,0.f); r.w=fmaxf(r.w,0.f); }
  *(float4*)(o + b) = r;
}

// ---------------------------------------------------------------------------
// WG0[t][g] = Wg0 @ zt0_t (ts0 baked into B staging). grid (16, 24).
__launch_bounds__(256)
__global__ void wg0_kernel(const float* __restrict__ Wz, const float* __restrict__ Wr,
                           const float* __restrict__ Wh, const float* __restrict__ X,
                           const float* __restrict__ ts0, float* __restrict__ WG0){
  int tile = blockIdx.x, by = blockIdx.y;
  int t = by / 3, g = by - t*3;
  const float* W = (g==0) ? Wz : (g==1) ? Wr : Wh;
  const float* Xt = X + (long)t * 1048576;
  int m0 = (tile >> 2) << 6, j0 = (tile & 3) << 6;
  int tid = threadIdx.x, lane = tid & 63, wave = tid >> 6;
  int ln31 = lane & 31, lhi = lane >> 5;
  int wm = (wave >> 1) << 5, wn = (wave & 1) << 5;
  __shared__ __align__(16) char LDSw[32768];
  u16* sAh = (u16*)LDSw;          u16* sAl = (u16*)(LDSw + 8192);
  u16* sBh = (u16*)(LDSw + 16384); u16* sBl = (u16*)(LDSw + 24576);
  f32x16 acc;
  #pragma unroll
  for (int i = 0; i < 16; i++) acc[i] = 0.f;
  for (int kk = 0; kk < 4; kk++){
    long k0 = (long)kk << 6;
    stage_f32s(W + (long)m0*256, 256, 64, k0, nullptr, sAh, sAl, tid);
    stage_f32s(Xt + (long)j0*256, 256, 64, k0, ts0 + t*256 + j0, sBh, sBl, tid);
    __syncthreads();
    #pragma unroll
    for (int s = 0; s < 4; s++){
      int kb = (s << 5) + (lhi << 4);
      acc = mm3(frag(sAh, wm+ln31, kb), frag(sAl, wm+ln31, kb),
                frag(sBh, wn+ln31, kb), frag(sBl, wn+ln31, kb), acc);
    }
    __syncthreads();
  }
  float* o = WG0 + (long)by * 65536;
  int rb = lhi << 2;
  #pragma unroll
  for (int reg = 0; reg < 16; reg++){
    int r = (reg & 3) + ((reg >> 2) << 3) + rb;
    o[(long)(m0 + wm + r)*256 + j0 + wn + ln31] = acc[reg];
  }
}

// ---------------------------------------------------------------------------
// K=256 MFMA GEMM: A fp32 [M][256] (inline split), B pre-split bf16 [256][256].
// mode 0: Cout = relu(A@B) fp32.  mode 1: write (A@B)^T split bf16.
__launch_bounds__(256, 2)
__global__ void gemm_k256(const float* __restrict__ A,
                          const u16* __restrict__ Bh, const u16* __restrict__ Bl,
                          float* __restrict__ Cout, u16* __restrict__ TH, u16* __restrict__ TL,
                          long ldT, int mode){
  int m0 = blockIdx.x << 7, n0 = blockIdx.y << 7;
  int tid = threadIdx.x, lane = tid & 63, wave = tid >> 6;
  int ln31 = lane & 31, lhi = lane >> 5;
  int wm = (wave >> 1) << 6, wn = (wave & 1) << 6;
  __shared__ __align__(16) char LDSg[66560];
  u16* sAh = (u16*)LDSg;            u16* sAl = (u16*)(LDSg + 16384);
  u16* sBh = (u16*)(LDSg + 32768);  u16* sBl = (u16*)(LDSg + 49152);
  f32x16 acc00, acc01, acc10, acc11;
  #pragma unroll
  for (int i = 0; i < 16; i++){ acc00[i]=0.f; acc01[i]=0.f; acc10[i]=0.f; acc11[i]=0.f; }
  for (int kk = 0; kk < 4; kk++){
    long k0 = (long)kk << 6;
    stage_f32s(A + (long)m0*256, 256, 128, k0, nullptr, sAh, sAl, tid);
    stage_cp(Bh + (long)n0*256, Bl + (long)n0*256, 256, 128, k0, sBh, sBl, tid);
    __syncthreads();
    #pragma unroll
    for (int s = 0; s < 4; s++){
      int kb = (s << 5) + (lhi << 4);
      bhalf8 a0h = frag(sAh, wm+ln31, kb),    a0l = frag(sAl, wm+ln31, kb);
      bhalf8 a1h = frag(sAh, wm+32+ln31, kb), a1l = frag(sAl, wm+32+ln31, kb);
      bhalf8 b0h = frag(sBh, wn+ln31, kb),    b0l = frag(sBl, wn+ln31, kb);
      bhalf8 b1h = frag(sBh, wn+32+ln31, kb), b1l = frag(sBl, wn+32+ln31, kb);
      acc00 = mm3(a0h, a0l, b0h, b0l, acc00);
      acc01 = mm3(a0h, a0l, b1h, b1l, acc01);
      acc10 = mm3(a1h, a1l, b0h, b0l, acc10);
      acc11 = mm3(a1h, a1l, b1h, b1l, acc11);
    }
    __syncthreads();
  }
  int rb = lhi << 2;
  if (mode == 0){
    float* o = Cout + (long)(m0 + wm)*256 + n0 + wn;
    #pragma unroll
    for (int reg = 0; reg < 16; reg++){
      int r = (reg & 3) + ((reg >> 2) << 3) + rb;
      o[(long)r*256 + ln31]             = fmaxf(acc00[reg], 0.f);
      o[(long)r*256 + 32 + ln31]        = fmaxf(acc01[reg], 0.f);
      o[(long)(r+32)*256 + ln31]        = fmaxf(acc10[reg], 0.f);
      o[(long)(r+32)*256 + 32 + ln31]   = fmaxf(acc11[reg], 0.f);
    }
  } else {
    float* ldsT = (float*)LDSg;   // [128][129]
    #pragma unroll
    for (int reg = 0; reg < 16; reg++){
      int r = (reg & 3) + ((reg >> 2) << 3) + rb;
      ldsT[(wm + r)*129 + wn + ln31]           = acc00[reg];
      ldsT[(wm + r)*129 + wn + 32 + ln31]      = acc01[reg];
      ldsT[(wm + 32 + r)*129 + wn + ln31]      = acc10[reg];
      ldsT[(wm + 32 + r)*129 + wn + 32 + ln31] = acc11[reg];
    }
    __syncthreads();
    int nl = tid >> 1, seg = tid & 1;
    u16* ph = TH + (long)(n0 + nl)*ldT + m0 + (seg << 6);
    u16* pl = TL + (long)(n0 + nl)*ldT + m0 + (seg << 6);
    #pragma unroll
    for (int q = 0; q < 8; q++){
      unsigned hh[8], ll[8];
      #pragma unroll
      for (int j = 0; j < 8; j++)
        split2(ldsT[(seg*64 + q*8 + j)*129 + nl], hh[j], ll[j]);
      uint4 vh, vl;
      vh.x = hh[0]|(hh[1]<<16); vh.y = hh[2]|(hh[3]<<16); vh.z = hh[4]|(hh[5]<<16); vh.w = hh[6]|(hh[7]<<16);
      vl.x = ll[0]|(ll[1]<<16); vl.y = ll[2]|(ll[3]<<16); vl.z = ll[4]|(ll[5]<<16); vl.w = ll[6]|(ll[7]<<16);
      ((uint4*)ph)[q] = vh;
      ((uint4*)pl)[q] = vl;
    }
  }
}

// ---------------------------------------------------------------------------
// ----------------------- persistent scan kernel ----------------------------
__device__ __forceinline__ void gbar(int* bar, int target){
  __syncthreads();
  if (threadIdx.x == 0){
    __threadfence();
    atomicAdd(bar, 1);
    while (__hip_atomic_load(bar, __ATOMIC_ACQUIRE, __HIP_MEMORY_SCOPE_AGENT) < target)
      __builtin_amdgcn_s_sleep(1);
    __threadfence();
  }
  __syncthreads();
}

// one 64x64 tile of a gate. Optional W-term (A=W presplit, B=zt from H1*ts1).
// U-term ONLY for g<2 (R3 fix: g==2's U-term belongs to phase_update with r*Q).
// g: 0=z(sig), 1=r(sig, transposed out), 2=raw W-term (HW).
__device__ void phase_gates(int g, int tile,
    const u16* WH_, const u16* WL_, const float* H1_, const float* ts1_,
    const u16* UH_, const u16* UL_, const u16* QTH_, const u16* QTL_,
    const float* addmat, const float* bias,
    float* zout, float* rTout, float* hwout, char* LDSp, int tid)
{
  int m0 = (tile >> 2) << 6, j0 = (tile & 3) << 6;
  u16* sA1h = (u16*)LDSp;             u16* sA1l = (u16*)(LDSp + 8192);
  u16* sB1h = (u16*)(LDSp + 16384);   u16* sB1l = (u16*)(LDSp + 24576);
  u16* sA2h = (u16*)(LDSp + 32768);   u16* sA2l = (u16*)(LDSp + 40960);
  u16* sB2h = (u16*)(LDSp + 49152);   u16* sB2l = (u16*)(LDSp + 57344);
  int lane = tid & 63, wave = tid >> 6;
  int ln31 = lane & 31, lhi = lane >> 5;
  int wm = (wave >> 1) << 5, wn = (wave & 1) << 5;
  bool doU = (g < 2);                  // R3 FIX
  f32x16 acc;
  #pragma unroll
  for (int i = 0; i < 16; i++) acc[i] = 0.f;
  for (int kk = 0; kk < 4; kk++){
    long k0 = (long)kk << 6;
    if (WH_){
      stage_cp(WH_ + (long)m0*256, WL_ + (long)m0*256, 256, 64, k0, sA1h, sA1l, tid);
      stage_f32s(H1_ + (long)j0*256, 256, 64, k0, ts1_ + j0, sB1h, sB1l, tid);
    }
    if (doU){
      stage_cp(UH_ + (long)m0*256, UL_ + (long)m0*256, 256, 64, k0, sA2h, sA2l, tid);
      stage_cp(QTH_ + (long)j0*256, QTL_ + (long)j0*256, 256, 64, k0, sB2h, sB2l, tid);
    }
    __syncthreads();
    #pragma unroll
    for (int s = 0; s < 4; s++){
      int kb = (s << 5) + (lhi << 4);
      if (WH_)
        acc = mm3(frag(sA1h, wm+ln31, kb), frag(sA1l, wm+ln31, kb),
                  frag(sB1h, wn+ln31, kb), frag(sB1l, wn+ln31, kb), acc);
      if (doU)
        acc = mm3(frag(sA2h, wm+ln31, kb), frag(sA2l, wm+ln31, kb),
                  frag(sB2h, wn+ln31, kb), frag(sB2l, wn+ln31, kb), acc);
    }
    __syncthreads();
  }
  int rb = lhi << 2;
  if (g == 0){
    #pragma unroll
    for (int reg = 0; reg < 16; reg++){
      int r = (reg & 3) + ((reg >> 2) << 3) + rb;
      int gm = m0 + wm + r, gj = j0 + wn + ln31;
      float v = acc[reg];
      if (addmat) v += addmat[gm*256 + gj];
      v += bias[gm*256 + gj];
      zout[gm*256 + gj] = 1.f/(1.f + __expf(-v));
    }
  } else if (g == 1){
    float* ldsT = (float*)LDSp;
    #pragma unroll
    for (int reg = 0; reg < 16; reg++){
      int r = (reg & 3) + ((reg >> 2) << 3) + rb;
      int gm = m0 + wm + r, gj = j0 + wn + ln31;
      float v = acc[reg];
      if (addmat) v += addmat[gm*256 + gj];
      v += bias[gm*256 + gj];
      ldsT[(wm + r)*65 + wn + ln31] = 1.f/(1.f + __expf(-v));
    }
    __syncthreads();
    twrite_f32(ldsT, rTout, m0, j0, tid);
  } else {
    #pragma unroll
    for (int reg = 0; reg < 16; reg++){
      int r = (reg & 3) + ((reg >> 2) << 3) + rb;
      int gm = m0 + wm + r, gj = j0 + wn + ln31;
      hwout[gm*256 + gj] = acc[reg];
    }
  }
}

// one 64x64 tile of the GRU update: Qn = (1-z)Q + z*tanh(Uh@(r*Q) + HW + bh)
__device__ void phase_update(int tile, const u16* UHh, const u16* UHl,
    const float* rT, const float* zb, const float* QTfC, const float* QfC,
    const float* HW, const float* bh,
    float* QfN, float* QTfN, u16* QThN, u16* QTlN, char* LDSp, int tid)
{
  int m0 = (tile >> 2) << 6, j0 = (tile & 3) << 6;
  u16* sAh = (u16*)LDSp;            u16* sAl = (u16*)(LDSp + 8192);
  u16* sBh = (u16*)(LDSp + 16384);  u16* sBl = (u16*)(LDSp + 24576);
  int lane = tid & 63, wave = tid >> 6;
  int ln31 = lane & 31, lhi = lane >> 5;
  int wm = (wave >> 1) << 5, wn = (wave & 1) << 5;
  f32x16 acc;
  #pragma unroll
  for (int i = 0; i < 16; i++) acc[i] = 0.f;
  for (int kk = 0; kk < 4; kk++){
    long k0 = (long)kk << 6;
    stage_cp(UHh + (long)m0*256, UHl + (long)m0*256, 256, 64, k0, sAh, sAl, tid);
    stage_prod(rT + (long)j0*256, QTfC + (long)j0*256, 256, 64, k0, sBh, sBl, tid);
    __syncthreads();
    #pragma unroll
    for (int s = 0; s < 4; s++){
      int kb = (s << 5) + (lhi << 4);
      acc = mm3(frag(sAh, wm+ln31, kb), frag(sAl, wm+ln31, kb),
                frag(sBh, wn+ln31, kb), frag(sBl, wn+ln31, kb), acc);
    }
    __syncthreads();
  }
  float* ldsT = (float*)LDSp;
  int rb = lhi << 2;
  #pragma unroll
  for (int reg = 0; reg < 16; reg++){
    int r = (reg & 3) + ((reg >> 2) << 3) + rb;
    int gm = m0 + wm + r, gj = j0 + wn + ln31;
    float hc = tanhf(acc[reg] + HW[gm*256 + gj] + bh[gm*256 + gj]);
    float z  = zb[gm*256 + gj];
    float qc = QfC[gm*256 + gj];
    float qn = (1.f - z)*qc + z*hc;
    QfN[gm*256 + gj] = qn;
    ldsT[(wm + r)*65 + wn + ln31] = qn;
  }
  __syncthreads();
  twrite_f32(ldsT, QTfN, m0, j0, tid);
  twrite_bf16(ldsT, QThN, QTlN, m0, j0, tid);
}

// 32-row slab of H1 = relu(Asrc @ Q0n) + fused layer-1 scores.
__device__ void phase_C(int blk8, const float* Asrc,
    const u16* QTh_, const u16* QTl_, const float* sc1, const float* sn,
    float* H1, float* ts1, char* LDSp, int tid)
{
  int m0 = blk8 << 5;
  u16* sBh = (u16*)LDSp;              // 256x64 = 32 KB
  u16* sBl = (u16*)(LDSp + 32768);
  u16* sAh = (u16*)(LDSp + 65536);    // 32x64 = 4 KB
  u16* sAl = (u16*)(LDSp + 69632);
  float* part = (float*)(LDSp + 73728); // [4][32]
  int lane = tid & 63, wave = tid >> 6;
  int ln31 = lane & 31, lhi = lane >> 5;
  int wnc = wave << 6;
  f32x16 a0, a1;
  #pragma unroll
  for (int i = 0; i < 16; i++){ a0[i]=0.f; a1[i]=0.f; }
  for (int kk = 0; kk < 4; kk++){
    long k0 = (long)kk << 6;
    stage_f32s(Asrc + (long)m0*256, 256, 32, k0, nullptr, sAh, sAl, tid);
    stage_cp(QTh_, QTl_, 256, 256, k0, sBh, sBl, tid);
    __syncthreads();
    #pragma unroll
    for (int s = 0; s < 4; s++){
      int kb = (s << 5) + (lhi << 4);
      bhalf8 ah = frag(sAh, ln31, kb), al = frag(sAl, ln31, kb);
      a0 = mm3(ah, al, frag(sBh, wnc+ln31, kb),    frag(sBl, wnc+ln31, kb),    a0);
      a1 = mm3(ah, al, frag(sBh, wnc+32+ln31, kb), frag(sBl, wnc+32+ln31, kb), a1);
    }
    __syncthreads();
  }
  int rb = lhi << 2;
  float s0 = sc1[wnc + ln31], s1 = sc1[wnc + 32 + ln31];
  #pragma unroll
  for (int reg = 0; reg < 16; reg++){
    int r = (reg & 3) + ((reg >> 2) << 3) + rb;
    float v0 = fmaxf(a0[reg], 0.f), v1 = fmaxf(a1[reg], 0.f);
    H1[(long)(m0 + r)*256 + wnc + ln31]      = v0;
    H1[(long)(m0 + r)*256 + wnc + 32 + ln31] = v1;
    float c = v0*s0 + v1*s1;
    c += __shfl_xor(c, 1);  c += __shfl_xor(c, 2);  c += __shfl_xor(c, 4);
    c += __shfl_xor(c, 8);  c += __shfl_xor(c, 16);
    if (ln31 == 0) part[wave*32 + r] = c;
  }
  __syncthreads();
  if (tid < 32){
    float s = part[tid] + part[32 + tid] + part[64 + tid] + part[96 + tid];
    ts1[m0 + tid] = tanhf(s / sn[1]);
  }
}

__launch_bounds__(256, 1)
__global__ void scan_kernel(
    float* __restrict__ Qf, float* __restrict__ QTf,
    u16* __restrict__ QTh, u16* __restrict__ QTl,
    const u16* __restrict__ SPL, const float* __restrict__ WG0,
    float* __restrict__ zb0, float* __restrict__ rT0,
    float* __restrict__ zb1, float* __restrict__ rT1,
    float* __restrict__ HW1, float* __restrict__ H1, float* __restrict__ ts1,
    const float* __restrict__ Bmat, const float* __restrict__ C7,
    const float* __restrict__ bz0, const float* __restrict__ br0, const float* __restrict__ bh0,
    const float* __restrict__ bz1, const float* __restrict__ br1, const float* __restrict__ bh1,
    const float* __restrict__ sc1, const float* __restrict__ sn,
    int* __restrict__ bar)
{
  __shared__ __align__(16) char LDS[81920];
  int blk = blockIdx.x, tid = threadIdx.x;
  int round = 0;

  // initial layer-0 gates for t=0 (pp = 0)
  if (blk < 32){
    int g = blk >> 4, tile = blk & 15;
    phase_gates(g, tile, nullptr, nullptr, nullptr, nullptr,
                SPL + (long)g*131072, SPL + (long)g*131072 + 65536,
                QTh, QTl,
                WG0 + (long)g*65536,
                (g==0) ? bz0 : br0,
                zb0, rT0, nullptr, LDS, tid);
  }
  gbar(bar, (++round) << 6);

  for (int t = 0; t < 8; t++){
    int cur = t & 1, nxt = cur ^ 1;
    long q0c = (long)cur*65536,          q0n = (long)nxt*65536;
    long q1c = 131072 + (long)cur*65536, q1n = 131072 + (long)nxt*65536;

    // B0: layer-0 update
    if (blk < 16)
      phase_update(blk, SPL + 2L*131072, SPL + 2L*131072 + 65536,
                   rT0, zb0, QTf + q0c, Qf + q0c,
                   WG0 + (long)(t*3 + 2)*65536, bh0,
                   Qf + q0n, QTf + q0n, QTh + q0n, QTl + q0n, LDS, tid);
    gbar(bar, (++round) << 6);

    // C: H1 slab + fused scores
    if (blk < 8)
      phase_C(blk, (t < 7) ? (Bmat + (long)t*65536) : C7,
              QTh + q0n, QTl + q0n, sc1, sn, H1, ts1, LDS, tid);
    gbar(bar, (++round) << 6);

    // A1: layer-1 gates (W-term for all g; U-term only g<2)
    if (blk < 48){
      int g = blk >> 4, tile = blk & 15;
      phase_gates(g, tile,
                  SPL + (long)(3+g)*131072, SPL + (long)(3+g)*131072 + 65536, H1, ts1,
                  SPL + (long)(6+g)*131072, SPL + (long)(6+g)*131072 + 65536,
                  QTh + q1c, QTl + q1c,
                  nullptr,
                  (g==0) ? bz1 : (g==1) ? br1 : nullptr,
                  zb1, rT1, HW1, LDS, tid);
    }
    gbar(bar, (++round) << 6);

    // merged: B1 (layer-1 update) || A0 of t+1
    if (blk < 16)
      phase_update(blk, SPL + 8L*131072, SPL + 8L*131072 + 65536,
                   rT1, zb1, QTf + q1c, Qf + q1c,
                   HW1, bh1,
                   Qf + q1n, QTf + q1n, QTh + q1n, QTl + q1n, LDS, tid);
    else if (blk < 48 && t < 7){
      int bb = blk - 16, g = bb >> 4, tile = bb & 15;
      phase_gates(g, tile, nullptr, nullptr, nullptr, nullptr,
                  SPL + (long)g*131072, SPL + (long)g*131072 + 65536,
                  QTh + q0n, QTl + q0n,
                  WG0 + (long)((t+1)*3 + g)*65536,
                  (g==0) ? bz0 : br0,
                  zb0, rT0, nullptr, LDS, tid);
    }
    gbar(bar, (++round) << 6);
  }
}

// ---------------------------------------------------------------------------
extern "C" void kernel_launch(void* const* d_in, const int* in_sizes, int n_in,
                              void* d_out, int out_size, void* d_ws, size_t ws_size,
                              hipStream_t stream){
  (void)in_sizes; (void)n_in; (void)out_size; (void)ws_size;
  const int N = 4096, F = 256;

  const float* A = (const float*)d_in[0];
  const float* X = (const float*)d_in[1];
  const float *SC[2], *WZ[2], *UZ[2], *BZ[2], *WR[2], *UR[2], *BR[2], *WH[2], *UH[2], *BH[2], *Q0I[2];
  for (int l = 0; l < 2; l++){
    int b = 3 + l*11;
    SC[l]  = (const float*)d_in[b+0];
    WZ[l]  = (const float*)d_in[b+1];  UZ[l] = (const float*)d_in[b+2];  BZ[l] = (const float*)d_in[b+3];
    WR[l]  = (const float*)d_in[b+4];  UR[l] = (const float*)d_in[b+5];  BR[l] = (const float*)d_in[b+6];
    WH[l]  = (const float*)d_in[b+7];  UH[l] = (const float*)d_in[b+8];  BH[l] = (const float*)d_in[b+9];
    Q0I[l] = (const float*)d_in[b+10];
  }

  char* w = (char*)d_ws;
  float* sn   = (float*)w;                    // 2 floats
  int*   bar  = (int*)(w + 64);
  float* ts0  = (float*)(w + 1024);           // 8*256
  float* ts1  = ts0 + 2048;                   // 256
  float* Qf   = ts1 + 256;                    // [2][2][65536]
  float* QTf  = Qf + 262144;
  u16*   QTh  = (u16*)(QTf + 262144);         // [2][2][65536] u16
  u16*   QTl  = QTh + 262144;
  float* zb0  = (float*)(QTl + 262144);
  float* rT0  = zb0 + 65536;
  float* zb1  = rT0 + 65536;
  float* rT1  = zb1 + 65536;
  float* HW1  = rT1 + 65536;
  float* H1s  = HW1 + 65536;
  float* WG0  = H1s + 65536;                  // [24][65536]
  u16*   SPL  = (u16*)(WG0 + 1572864);        // [9][131072] u16
  float* Bmat = (float*)(SPL + 1179648);      // [7][65536]
  float* C7   = Bmat + 458752;                // [4096][256]
  float* H1f  = C7 + 1048576;                 // [4096][256]
  u16* A7H = (u16*)(H1f + 1048576);           // [4096][4096] hi
  u16* A7L = A7H + 16777216;
  u16* ArH = A7L + 16777216;                  // [7][256][4096]
  u16* ArL = ArH + 7340032;
  u16* XtH = ArL + 7340032;                   // [8][256][4096]
  u16* XtL = XtH + 8388608;
  u16* ZTh = XtL + 8388608;                   // [256][4096]
  u16* ZTl = ZTh + 1048576;
  float* PB = (float*)(ZTl + 1048576);        // [7][4][65536]
  float* PC = PB + 1835008;                   // [4][1048576]

  // ---- pre-phase ----
  norm_kernel<<<1, 256, 0, stream>>>(SC[0], SC[1], sn, bar);
  scores_kernel<<<dim3(64, 8), 256, 0, stream>>>(X, (long)N*F, SC[0], sn, 0, ts0, 256);
  prepq_kernel<<<dim3(64, 2), 256, 0, stream>>>(Q0I[0], Q0I[1], Qf, QTf, QTh, QTl);
  split9_kernel<<<dim3(32, 9), 256, 0, stream>>>(UZ[0], UR[0], UH[0],
                                                 WZ[1], WR[1], WH[1],
                                                 UZ[1], UR[1], UH[1], SPL);
  split_kernel<<<dim3(8192, 1), 256, 0, stream>>>(A + (long)7*N*N, 0, A7H, A7L, 0, 2097152);
  split_kernel<<<dim3(512, 7), 256, 0, stream>>>(A, (long)N*N, ArH, ArL, 1048576, 131072);
  tconv_kernel<<<dim3(128, 8, 8), 256, 0, stream>>>(X, 1048576, XtH, XtL, 1048576);
  gemm_mfma<<<dim3(2, 2, 28), 256, 0, stream>>>(ArH, ArL, 1048576, XtH, XtL, 1048576, PB, 262144);
  gemm_mfma<<<dim3(32, 2, 4), 256, 0, stream>>>(A7H, A7L, 0, XtH + 7*1048576, XtL + 7*1048576, 0, PC, 0);
  reduce4_kernel<<<dim3(64, 7), 256, 0, stream>>>(PB, 262144, 65536, Bmat, 65536, 16384, 0);
  reduce4_kernel<<<dim3(1024, 1), 256, 0, stream>>>(PC, 0, 1048576, C7, 0, 262144, 0);
  wg0_kernel<<<dim3(16, 24), 256, 0, stream>>>(WZ[0], WR[0], WH[0], X, ts0, WG0);

  // ---- persistent scan (both layers, 8 timesteps) ----
  scan_kernel<<<64, 256, 0, stream>>>(Qf, QTf, QTh, QTl, SPL, WG0,
                                      zb0, rT0, zb1, rT1, HW1, H1s, ts1,
                                      Bmat, C7,
                                      BZ[0], BR[0], BH[0], BZ[1], BR[1], BH[1],
                                      SC[1], sn, bar);

  // ---- final: H1full = relu(C7@Q0f); ZT = (H1full@Q1f)^T; out = relu(A7@Z) ----
  gemm_k256<<<dim3(32, 2), 256, 0, stream>>>(C7, QTh, QTl, H1f, nullptr, nullptr, 0, 0);
  gemm_k256<<<dim3(32, 2), 256, 0, stream>>>(H1f, QTh + 131072, QTl + 131072,
                                             nullptr, ZTh, ZTl, 4096, 1);
  gemm_mfma<<<dim3(32, 2, 4), 256, 0, stream>>>(A7H, A7L, 0, ZTh, ZTl, 0, PC, 0);
  reduce4_kernel<<<dim3(1024, 1), 256, 0, stream>>>(PC, 0, 1048576, (float*)d_out, 0, 262144, 1);
}